// Round 12
// baseline (1159.981 us; speedup 1.0000x reference)
//
#include <hip/hip_runtime.h>
#include <cstdint>
#include <cstddef>

typedef __bf16 bf16x8 __attribute__((ext_vector_type(8)));
typedef float f32x4 __attribute__((ext_vector_type(4)));
typedef float f32x2 __attribute__((ext_vector_type(2)));
typedef unsigned short us16;

__device__ __forceinline__ float lrelu(float v) { return v >= 0.0f ? v : 0.01f * v; }
__device__ __forceinline__ float fsigmoid(float x) {
  x = fminf(fmaxf(x, -30.0f), 30.0f);
  return 1.0f / (1.0f + __expf(-x));
}
__device__ __forceinline__ float ftanh(float x) {
  x = fminf(fmaxf(x, -15.0f), 15.0f);
  float e = __expf(2.0f * x);
  return (e - 1.0f) / (e + 1.0f);
}
__device__ __forceinline__ us16 f2b(float f) {
  unsigned int u = __builtin_bit_cast(unsigned int, f);
  u = (u + 0x7fffu + ((u >> 16) & 1u)) >> 16;
  return (us16)u;
}
__device__ __forceinline__ float b2f(us16 h) {
  unsigned int u = ((unsigned int)h) << 16;
  return __builtin_bit_cast(float, u);
}
__device__ __forceinline__ unsigned pk2(float a, float b) {
  return (unsigned)f2b(a) | ((unsigned)f2b(b) << 16);
}
// fp8 e4m3 (OCP) encode/decode via gfx950 HW converts
__device__ __forceinline__ unsigned char f2f8(float v) {
  return (unsigned char)(__builtin_amdgcn_cvt_pk_fp8_f32(v, v, 0, false) & 0xFF);
}
__device__ __forceinline__ void unpf8(int2 v, float* t) {
  f32x2 p0 = __builtin_amdgcn_cvt_pk_f32_fp8(v.x, false);
  f32x2 p1 = __builtin_amdgcn_cvt_pk_f32_fp8(v.x, true);
  f32x2 p2 = __builtin_amdgcn_cvt_pk_f32_fp8(v.y, false);
  f32x2 p3 = __builtin_amdgcn_cvt_pk_f32_fp8(v.y, true);
  t[0] = p0.x; t[1] = p0.y; t[2] = p1.x; t[3] = p1.y;
  t[4] = p2.x; t[5] = p2.y; t[6] = p3.x; t[7] = p3.y;
}

// async global->LDS, 16B per lane
__device__ __forceinline__ void stage16(const us16* gsrc, us16* ldst) {
  __builtin_amdgcn_global_load_lds(
      (const __attribute__((address_space(1))) unsigned int*)(const void*)gsrc,
      (__attribute__((address_space(3))) unsigned int*)(void*)ldst, 16, 0, 0);
}
// 128B-row tiles (Kstep=64): slot = chunk ^ (row&7)
__device__ __forceinline__ bf16x8 frag_rd(const us16* base, int row, int byte_in_row) {
  int byte = row * 128 + (byte_in_row ^ ((row & 7) << 4));
  return *(const bf16x8*)((const char*)base + byte);
}
// 64B-row tiles (Kstep=32): slot = chunk ^ ((row>>1)&3)
__device__ __forceinline__ bf16x8 frd32(const us16* tilebase, int row, int ck16) {
  int slot = ck16 ^ ((row >> 1) & 3);
  return *(const bf16x8*)(tilebase + row * 32 + slot * 8);
}

// ---------------- degree / CSR build ----------------
__global__ void k_deg(const int* __restrict__ dst, int* __restrict__ indeg, int E) {
  int e = blockIdx.x * 256 + threadIdx.x;
  if (e < E) atomicAdd(&indeg[dst[e]], 1);
}

__global__ __launch_bounds__(1024) void k_scan1(const int* __restrict__ v, int* __restrict__ rp,
                                                int* __restrict__ part, float* __restrict__ dis, int n) {
  __shared__ int wsum[16];
  int base = blockIdx.x << 10;
  int t = threadIdx.x, lane = t & 63, wv = t >> 6;
  int val = (base + t < n) ? v[base + t] : 0;
  if (base + t < n) dis[base + t] = rsqrtf((float)(val + 1));
  int s = val;
  #pragma unroll
  for (int off = 1; off < 64; off <<= 1) {
    int u = __shfl_up(s, off);
    if (lane >= off) s += u;
  }
  if (lane == 63) wsum[wv] = s;
  __syncthreads();
  int wadd = 0;
  #pragma unroll
  for (int w = 0; w < 16; ++w) wadd += (w < wv) ? wsum[w] : 0;
  if (base + t < n) rp[base + t] = wadd + s - val;
  if (t == 0) {
    int tot = 0;
    #pragma unroll
    for (int w = 0; w < 16; ++w) tot += wsum[w];
    part[blockIdx.x] = tot;
  }
}

__global__ __launch_bounds__(1024) void k_scan2(int* __restrict__ p, int nc) {
  __shared__ int wsum[16];
  int t = threadIdx.x, lane = t & 63, wv = t >> 6;
  int val = (t < nc) ? p[t] : 0;
  int s = val;
  #pragma unroll
  for (int off = 1; off < 64; off <<= 1) {
    int u = __shfl_up(s, off);
    if (lane >= off) s += u;
  }
  if (lane == 63) wsum[wv] = s;
  __syncthreads();
  int wadd = 0;
  #pragma unroll
  for (int w = 0; w < 16; ++w) wadd += (w < wv) ? wsum[w] : 0;
  if (t < nc) p[t] = wadd + s - val;
}

__global__ void k_scan3(int* __restrict__ rp, const int* __restrict__ part,
                        int* __restrict__ cursor, int n, int total) {
  int i = blockIdx.x * 256 + threadIdx.x;
  if (i < n) {
    int v = rp[i] + part[i >> 10];
    rp[i] = v;
    cursor[i] = v;
  } else if (i == n) {
    rp[n] = total;
  }
}

__global__ void k_fill(const int* __restrict__ src, const int* __restrict__ dst,
                       const float* __restrict__ dis, int* __restrict__ cursor,
                       int* __restrict__ csrc, float* __restrict__ cw, int E) {
  int e = blockIdx.x * 256 + threadIdx.x;
  if (e >= E) return;
  int s = src[e], d = dst[e];
  int pos = atomicAdd(&cursor[d], 1);
  csrc[pos] = s;
  cw[pos] = dis[s] * dis[d];
}

// ---------------- repack: all three activation casts in one launch ----------------
__global__ void k_castall(const float* __restrict__ x, const float* __restrict__ p0,
                          const float* __restrict__ p1,
                          us16* __restrict__ xb, us16* __restrict__ p0b,
                          us16* __restrict__ p1b, int N) {
  int i = (blockIdx.x * 256 + threadIdx.x) * 4;
  const int nx = N * 128, n0 = N * 256;
  const float* src;
  us16* dst;
  int off;
  if (i < nx) { src = x; dst = xb; off = i; }
  else if (i < nx + n0) { src = p0; dst = p0b; off = i - nx; }
  else if (i < nx + n0 + nx) { src = p1; dst = p1b; off = i - nx - n0; }
  else return;
  float4 v = *(const float4*)(src + off);
  *(ushort4*)(dst + off) = make_ushort4(f2b(v.x), f2b(v.y), f2b(v.z), f2b(v.w));
}

__global__ void k_prepw(const float* __restrict__ Wih1, const float* __restrict__ Whh1,
                        const float* __restrict__ Wih2, const float* __restrict__ Whh2,
                        const float* __restrict__ Wp1, const float* __restrict__ Wp2,
                        const float* __restrict__ Wc1, const float* __restrict__ Wc2,
                        us16* __restrict__ Wih1b, us16* __restrict__ Whh1b,
                        us16* __restrict__ Wih2b, us16* __restrict__ Whh2b,
                        us16* __restrict__ WtP1, us16* __restrict__ WtP2,
                        us16* __restrict__ WtC1, us16* __restrict__ WtC2) {
  int e = blockIdx.x * 256 + threadIdx.x;
  if (e < 196608) { Wih1b[e] = f2b(Wih1[e]); return; }
  e -= 196608;
  if (e < 196608) { Whh1b[e] = f2b(Whh1[e]); return; }
  e -= 196608;
  if (e < 49152) { Wih2b[e] = f2b(Wih2[e]); return; }
  e -= 49152;
  if (e < 49152) { Whh2b[e] = f2b(Whh2[e]); return; }
  e -= 49152;
  if (e < 32768) { int r = e & 127, c = e >> 7; WtP1[e] = f2b(Wp1[(size_t)r * 256 + c]); return; }
  e -= 32768;
  if (e < 32768) { int r = e & 255, c = e >> 8; WtP2[e] = f2b(Wp2[(size_t)r * 128 + c]); return; }
  e -= 32768;
  if (e < 32768) { int r = e & 127, c = e >> 7; WtC1[e] = f2b(Wc1[(size_t)r * 256 + c]); return; }
  e -= 32768;
  if (e < 32768) { int r = e & 255, c = e >> 8; WtC2[e] = f2b(Wc2[(size_t)r * 128 + c]); }
}

// ---------------- bf16 MFMA GEMM (r11 T4 version): C = act(A @ Bt^T + bias) ----------------
template<int ACT, int BIAS, int OF8>
__global__ __launch_bounds__(256) void k_mm(const us16* __restrict__ A,
                                            const us16* __restrict__ Bt,
                                            const float* __restrict__ bias,
                                            void* __restrict__ Cout,
                                            int M, int K, int Nc, int ny) {
  __shared__ __align__(16) us16 lds[2][2 * 8192];
  const int bm = (blockIdx.x / ny) * 128;
  const int bn = (blockIdx.x % ny) * 128;
  const int tid = threadIdx.x;
  const int lane = tid & 63;
  const int wave = tid >> 6;
  const int wm = (wave >> 1) * 64;
  const int wn = (wave & 1) * 64;
  const int lr = lane & 15;
  const int lk = lane >> 4;
  const int srow = lane >> 3;
  const int schk = (lane & 7) ^ srow;
  f32x4 acc[4][4] = {};

  auto stage = [&](int k0, us16* buf) {
    #pragma unroll
    for (int it = 0; it < 4; ++it) {
      int r8 = (wave * 4 + it) * 8;
      int ar = bm + r8 + srow; if (ar >= M) ar = M - 1;
      stage16(A + (size_t)ar * K + k0 + schk * 8, buf + r8 * 64);
      stage16(Bt + (size_t)(bn + r8 + srow) * K + k0 + schk * 8, buf + 8192 + r8 * 64);
    }
  };

  const int nk = K >> 6;
  stage(0, lds[0]);
  for (int t = 0; t < nk; ++t) {
    us16* cur = lds[t & 1];
    if (t + 1 < nk) {
      if (t > 0) {
        asm volatile("s_waitcnt lgkmcnt(0)" ::: "memory");
        __builtin_amdgcn_s_barrier();
      }
      stage((t + 1) << 6, lds[(t + 1) & 1]);
      asm volatile("s_waitcnt vmcnt(8)" ::: "memory");
    } else {
      asm volatile("s_waitcnt vmcnt(0)" ::: "memory");
    }
    __builtin_amdgcn_s_barrier();
    #pragma unroll
    for (int kk = 0; kk < 2; ++kk) {
      bf16x8 af[4], bq[4];
      #pragma unroll
      for (int i = 0; i < 4; ++i) af[i] = frag_rd(cur, wm + i * 16 + lr, kk * 64 + lk * 16);
      #pragma unroll
      for (int j = 0; j < 4; ++j) bq[j] = frag_rd(cur + 8192, wn + j * 16 + lr, kk * 64 + lk * 16);
      #pragma unroll
      for (int i = 0; i < 4; ++i)
        #pragma unroll
        for (int j = 0; j < 4; ++j)
          acc[i][j] = __builtin_amdgcn_mfma_f32_16x16x32_bf16(af[i], bq[j], acc[i][j], 0, 0, 0);
    }
  }
  float bb[4];
  #pragma unroll
  for (int j = 0; j < 4; ++j) bb[j] = BIAS ? bias[bn + wn + j * 16 + lr] : 0.0f;
  #pragma unroll
  for (int i = 0; i < 4; ++i) {
    #pragma unroll
    for (int q = 0; q < 4; ++q) {
      int row = bm + wm + i * 16 + lk * 4 + q;
      if (row < M) {
        #pragma unroll
        for (int j = 0; j < 4; ++j) {
          int col = bn + wn + j * 16 + lr;
          float v = acc[i][j][q] + bb[j];
          if (ACT) v = lrelu(v);
          if (OF8) ((unsigned char*)Cout)[(size_t)row * Nc + col] = f2f8(v);
          else ((us16*)Cout)[(size_t)row * Nc + col] = f2b(v);
        }
      }
    }
  }
}

// ---------------- CSR aggregation, F=128, fp8 gather payload ----------------
template<int ACT>
__global__ __launch_bounds__(256) void k_agg128(const unsigned char* __restrict__ hw,
                                                const int* __restrict__ rp,
                                                const int* __restrict__ csrc, const float* __restrict__ cw,
                                                const float* __restrict__ dis, const float* __restrict__ bias,
                                                us16* __restrict__ outp, int M) {
  int node = blockIdx.x * 16 + (threadIdx.x >> 4);
  int l = threadIdx.x & 15;
  if (node >= M) return;
  const unsigned char* base = hw + l * 8;
  float acc[8], t0[8], t1[8], t2[8], t3[8];
  float dn = dis[node];
  float sw = dn * dn;
  {
    int2 v = *(const int2*)(base + (size_t)node * 128);
    unpf8(v, t0);
    #pragma unroll
    for (int j = 0; j < 8; ++j) acc[j] = t0[j] * sw;
  }
  int e = rp[node], e1 = rp[node + 1];
  for (; e + 4 <= e1; e += 4) {
    int s0 = csrc[e], s1 = csrc[e + 1], s2 = csrc[e + 2], s3 = csrc[e + 3];
    float w0 = cw[e], w1 = cw[e + 1], w2 = cw[e + 2], w3 = cw[e + 3];
    int2 v0 = *(const int2*)(base + (size_t)s0 * 128);
    int2 v1 = *(const int2*)(base + (size_t)s1 * 128);
    int2 v2 = *(const int2*)(base + (size_t)s2 * 128);
    int2 v3 = *(const int2*)(base + (size_t)s3 * 128);
    unpf8(v0, t0); unpf8(v1, t1); unpf8(v2, t2); unpf8(v3, t3);
    #pragma unroll
    for (int j = 0; j < 8; ++j) acc[j] = fmaf(w0, t0[j], acc[j]);
    #pragma unroll
    for (int j = 0; j < 8; ++j) acc[j] = fmaf(w1, t1[j], acc[j]);
    #pragma unroll
    for (int j = 0; j < 8; ++j) acc[j] = fmaf(w2, t2[j], acc[j]);
    #pragma unroll
    for (int j = 0; j < 8; ++j) acc[j] = fmaf(w3, t3[j], acc[j]);
  }
  for (; e < e1; ++e) {
    int s0 = csrc[e];
    float w0 = cw[e];
    int2 v0 = *(const int2*)(base + (size_t)s0 * 128);
    unpf8(v0, t0);
    #pragma unroll
    for (int j = 0; j < 8; ++j) acc[j] = fmaf(w0, t0[j], acc[j]);
  }
  if (ACT) {
    float4 b0 = *(const float4*)(bias + l * 8);
    float4 b1 = *(const float4*)(bias + l * 8 + 4);
    float bb[8] = {b0.x, b0.y, b0.z, b0.w, b1.x, b1.y, b1.z, b1.w};
    #pragma unroll
    for (int j = 0; j < 8; ++j) acc[j] = lrelu(acc[j] + bb[j]);
  }
  int4 o;
  o.x = (int)pk2(acc[0], acc[1]);
  o.y = (int)pk2(acc[2], acc[3]);
  o.z = (int)pk2(acc[4], acc[5]);
  o.w = (int)pk2(acc[6], acc[7]);
  *(int4*)(outp + (size_t)node * 128 + l * 8) = o;
}

// ---------------- fused GRU cell: fat-tile role-split (MFMA), T4 counted-vmcnt ----------------
// Block 512 thr = 8 waves = 2 row-pairs x 2 roles x 2 col-halves. BM=128, BN=64.
// Wave tile 64 rows x 32 cols, 3 gates: acc[3][4][2] = 96 VGPR, 24 MFMA per 10 ds_read_b128
// (6.7 B/MFMA vs prior 10.7). K-step 32, dbuf LDS 2x40KB, counted vmcnt(5).
// Exchange gh->gi in 2 phases (48KB) at block end.
template<int H, int WB, int PH>
__global__ __launch_bounds__(512) void k_fgru(const us16* __restrict__ xb, const us16* __restrict__ hb,
                                              const us16* __restrict__ Wih, const us16* __restrict__ Whh,
                                              const float* __restrict__ bih, const float* __restrict__ bhh,
                                              float* __restrict__ emb, us16* __restrict__ embb,
                                              const float* __restrict__ Wpost, const float* __restrict__ bpost,
                                              float* __restrict__ outv, int M, int ny) {
  // buf layout (us16): x[128x32] @0 (4096) | h[128x32] @4096 | W[6][64x32] @8192+g*2048
  __shared__ __align__(16) us16 lds[2][20480];  // 40KB each
  const int nwg = gridDim.x;
  int bid = blockIdx.x;
  {  // bijective XCD-chunked remap
    int q8 = nwg >> 3, r8 = nwg & 7;
    int xc = bid & 7, ix = bid >> 3;
    bid = (xc < r8 ? xc * (q8 + 1) : r8 * (q8 + 1) + (xc - r8) * q8) + ix;
  }
  const int bn = (bid % ny) * 64;
  const int bm = (bid / ny) * 128;
  const int tid = threadIdx.x;
  const int lane = tid & 63, wave = tid >> 6;
  const int pair = wave >> 2;        // 0..1 -> 64-row group
  const int role = (wave >> 1) & 1;  // 0 = gi (x, Wih), 1 = gh (h, Whh)
  const int ch = wave & 1;           // col half (32 cols)
  const int lr = lane & 15, lk = lane >> 4;
  const int sl_row = lane >> 2;
  const int sl_chk = (lane & 3) ^ ((lane >> 3) & 3);

  f32x4 acc[3][4][2] = {};

  auto stage_step = [&](int k0, us16* buf) {
    #pragma unroll
    for (int it = 0; it < 5; ++it) {
      int m = wave * 5 + it;  // 0..39
      const us16* src;
      us16* dst;
      if (m < 16) {
        int r0 = (m & 7) * 16;
        int ar = bm + r0 + sl_row; if (ar >= M) ar = M - 1;
        src = (m < 8 ? xb : hb) + (size_t)ar * H + k0 + sl_chk * 8;
        dst = buf + (m < 8 ? 0 : 4096) + r0 * 32;
      } else {
        int wi = m - 16;            // 0..23
        int g6 = wi >> 2;           // 0..5 (0-2 Wih, 3-5 Whh)
        int r0 = (wi & 3) * 16;     // 0..48 (64 gate-cols per tile)
        const us16* W = (g6 < 3) ? Wih : Whh;
        int gg = (g6 < 3) ? g6 : g6 - 3;
        src = W + (size_t)(gg * H + bn + r0 + sl_row) * H + k0 + sl_chk * 8;
        dst = buf + 8192 + g6 * 2048 + r0 * 32;
      }
      stage16(src, dst);
    }
  };

  const int nk = H >> 5;
  stage_step(0, lds[0]);
  for (int t = 0; t < nk; ++t) {
    us16* cur = lds[t & 1];
    if (t + 1 < nk) {
      if (t > 0) {
        asm volatile("s_waitcnt lgkmcnt(0)" ::: "memory");
        __builtin_amdgcn_s_barrier();
      }
      stage_step((t + 1) << 5, lds[(t + 1) & 1]);
      asm volatile("s_waitcnt vmcnt(5)" ::: "memory");  // own stage(t) landed; 5 of stage(t+1) in flight
    } else {
      asm volatile("s_waitcnt vmcnt(0)" ::: "memory");
    }
    __builtin_amdgcn_s_barrier();
    const us16* at = cur + (role ? 4096 : 0);
    bf16x8 a[4];
    #pragma unroll
    for (int i = 0; i < 4; ++i) a[i] = frd32(at, pair * 64 + i * 16 + lr, lk);
    #pragma unroll
    for (int g = 0; g < 3; ++g) {
      const us16* wt = cur + 8192 + (role * 3 + g) * 2048;
      bf16x8 b0 = frd32(wt, ch * 32 + lr, lk);
      bf16x8 b1 = frd32(wt, ch * 32 + 16 + lr, lk);
      #pragma unroll
      for (int i = 0; i < 4; ++i) {
        acc[g][i][0] = __builtin_amdgcn_mfma_f32_16x16x32_bf16(a[i], b0, acc[g][i][0], 0, 0, 0);
        acc[g][i][1] = __builtin_amdgcn_mfma_f32_16x16x32_bf16(a[i], b1, acc[g][i][1], 0, 0, 0);
      }
    }
  }
  // ---- exchange (2 phases over col-halves) + epilogue in gi waves ----
  float* xch = (float*)&lds[0][0];  // 48KB: [pair][g][i][j][lane][4]
  #pragma unroll
  for (int ph = 0; ph < 2; ++ph) {
    __syncthreads();
    if (role == 1 && ch == ph) {
      #pragma unroll
      for (int g = 0; g < 3; ++g)
        #pragma unroll
        for (int i = 0; i < 4; ++i)
          #pragma unroll
          for (int j = 0; j < 2; ++j)
            *(f32x4*)&xch[((((pair * 3 + g) * 4 + i) * 2 + j) * 64 + lane) * 4] = acc[g][i][j];
    }
    __syncthreads();
    if (role == 0 && ch == ph) {
      float part[4][4] = {};
      #pragma unroll
      for (int j = 0; j < 2; ++j) {
        int col = bn + ch * 32 + j * 16 + lr;
        float bir = bih[col], biz = bih[H + col], bin = bih[2 * H + col];
        float bhr = bhh[col], bhz = bhh[H + col], bhn = bhh[2 * H + col];
        float wps = 0.0f;
        if (PH) wps = Wpost[2 * col] + Wpost[2 * col + 1];
        #pragma unroll
        for (int i = 0; i < 4; ++i) {
          f32x4 gr_ = *(const f32x4*)&xch[((((pair * 3 + 0) * 4 + i) * 2 + j) * 64 + lane) * 4];
          f32x4 gz_ = *(const f32x4*)&xch[((((pair * 3 + 1) * 4 + i) * 2 + j) * 64 + lane) * 4];
          f32x4 gn_ = *(const f32x4*)&xch[((((pair * 3 + 2) * 4 + i) * 2 + j) * 64 + lane) * 4];
          #pragma unroll
          for (int q = 0; q < 4; ++q) {
            int row = bm + pair * 64 + i * 16 + lk * 4 + q;
            if (row < M) {
              float r = fsigmoid(acc[0][i][j][q] + bir + gr_[q] + bhr);
              float z = fsigmoid(acc[1][i][j][q] + biz + gz_[q] + bhz);
              float n = ftanh(acc[2][i][j][q] + bin + r * (gn_[q] + bhn));
              float hv = b2f(hb[(size_t)row * H + col]);
              float o = (1.0f - z) * n + z * hv;
              emb[(size_t)row * H + col] = o;
              if (WB) embb[(size_t)row * H + col] = f2b(o);
              if (PH) part[i][q] += o * wps;
            }
          }
        }
      }
      if (PH) {
        float bsum = bpost[0] + bpost[1];
        #pragma unroll
        for (int i = 0; i < 4; ++i)
          #pragma unroll
          for (int q = 0; q < 4; ++q) {
            float v = part[i][q];
            v += __shfl_xor(v, 1); v += __shfl_xor(v, 2);
            v += __shfl_xor(v, 4); v += __shfl_xor(v, 8);
            int row = bm + pair * 64 + i * 16 + lk * 4 + q;
            if (lr == 0 && row < M)
              atomicAdd(&outv[row], v + ((bn == 0 && ch == 0) ? bsum : 0.0f));
          }
      }
    }
  }
}

extern "C" void kernel_launch(void* const* d_in, const int* in_sizes, int n_in,
                              void* d_out, int out_size, void* d_ws, size_t ws_size,
                              hipStream_t stream) {
  const float* x     = (const float*)d_in[0];
  const int*   ei    = (const int*)d_in[1];
  const float* prev0 = (const float*)d_in[2];
  const float* prev1 = (const float*)d_in[3];
  const float* Wp1   = (const float*)d_in[4];
  const float* bp1   = (const float*)d_in[5];
  const float* Wp2   = (const float*)d_in[6];
  const float* bp2   = (const float*)d_in[7];
  const float* Wc1   = (const float*)d_in[8];
  const float* bc1   = (const float*)d_in[9];
  const float* Wc2   = (const float*)d_in[10];
  const float* bc2   = (const float*)d_in[11];
  const float* Wih1  = (const float*)d_in[12];
  const float* Whh1  = (const float*)d_in[13];
  const float* bih1  = (const float*)d_in[14];
  const float* bhh1  = (const float*)d_in[15];
  const float* Wih2  = (const float*)d_in[16];
  const float* Whh2  = (const float*)d_in[17];
  const float* bih2  = (const float*)d_in[18];
  const float* bhh2  = (const float*)d_in[19];
  const float* Wpost = (const float*)d_in[20];
  const float* bpost = (const float*)d_in[21];

  const int N = in_sizes[0] / 128;   // 100000
  const int E = in_sizes[1] / 2;     // 1600000
  const int* srcp = ei;
  const int* dstp = ei + E;

  char* wsb = (char*)d_ws;
  size_t off = 0;
  auto alloc = [&](size_t bytes) -> void* {
    void* p = wsb + off;
    off = (off + bytes + 255) & ~(size_t)255;
    return p;
  };
  float* dis    = (float*)alloc((size_t)N * 4);
  int*   indeg  = (int*)alloc((size_t)N * 4);
  int*   rp     = (int*)alloc((size_t)(N + 1) * 4);
  int*   part   = (int*)alloc((size_t)1024 * 4);
  int*   cursor = (int*)alloc((size_t)N * 4);
  int*   csrc   = (int*)alloc((size_t)E * 4);
  float* cw     = (float*)alloc((size_t)E * 4);
  us16* xb    = (us16*)alloc((size_t)N * 128 * 2);
  us16* p0b   = (us16*)alloc((size_t)N * 256 * 2);
  us16* p1b   = (us16*)alloc((size_t)N * 128 * 2);
  us16* WtP1  = (us16*)alloc((size_t)256 * 128 * 2);
  us16* WtP2  = (us16*)alloc((size_t)128 * 256 * 2);
  us16* WtC1  = (us16*)alloc((size_t)256 * 128 * 2);
  us16* WtC2  = (us16*)alloc((size_t)128 * 256 * 2);
  us16* Wih1b = (us16*)alloc((size_t)768 * 256 * 2);
  us16* Whh1b = (us16*)alloc((size_t)768 * 256 * 2);
  us16* Wih2b = (us16*)alloc((size_t)384 * 128 * 2);
  us16* Whh2b = (us16*)alloc((size_t)384 * 128 * 2);
  us16* bufA  = (us16*)alloc((size_t)N * 256 * 2);           // MLP hidden / GCN1 out (bf16)
  unsigned char* buf8 = (unsigned char*)alloc((size_t)N * 128); // fp8 gather payload
  us16* bufD  = (us16*)alloc((size_t)N * 128 * 2);           // agg out (bf16)
  us16* emb0b = (us16*)alloc((size_t)N * 256 * 2);
  (void)ws_size; (void)n_in; (void)out_size;

  float* outv = (float*)d_out;
  float* emb0 = outv + N;
  float* emb1 = emb0 + (size_t)N * 256;

  // zero the post-head accumulator
  hipMemsetAsync(outv, 0, (size_t)N * 4, stream);

  // activation casts (single launch) + fused weight prep
  k_castall<<<((size_t)N * 512 / 4 + 255) / 256, 256, 0, stream>>>(x, prev0, prev1, xb, p0b, p1b, N);
  k_prepw<<<2432, 256, 0, stream>>>(Wih1, Whh1, Wih2, Whh2, Wp1, Wp2, Wc1, Wc2,
                                    Wih1b, Whh1b, Wih2b, Whh2b, WtP1, WtP2, WtC1, WtC2);

  // CSR build
  hipMemsetAsync(indeg, 0, (size_t)N * 4, stream);
  k_deg<<<(E + 255) / 256, 256, 0, stream>>>(dstp, indeg, E);
  const int NC = (N + 1023) / 1024;  // 98
  k_scan1<<<NC, 1024, 0, stream>>>(indeg, rp, part, dis, N);
  k_scan2<<<1, 1024, 0, stream>>>(part, NC);
  k_scan3<<<(N + 256) / 256, 256, 0, stream>>>(rp, part, cursor, N, E);
  k_fill<<<(E + 255) / 256, 256, 0, stream>>>(srcp, dstp, dis, cursor, csrc, cw, E);

  const int MB = (N + 127) / 128;   // 782
  const int AB = (N + 15) / 16;     // 6250

  // preprocess MLP (MLP2 writes fp8 gather payload)
  k_mm<1, 1, 0><<<MB * 2, 256, 0, stream>>>(xb, WtP1, bp1, bufA, N, 128, 256, 2);
  k_mm<1, 1, 1><<<MB, 256, 0, stream>>>(bufA, WtP2, bp2, buf8, N, 256, 128, 1);
  // GCN1: aggregate FIRST (linearity, fp8 gathers), then linear+bias+leaky
  k_agg128<0><<<AB, 256, 0, stream>>>(buf8, rp, csrc, cw, dis, nullptr, bufD, N);
  k_mm<1, 1, 0><<<MB * 2, 256, 0, stream>>>(bufD, WtC1, bc1, bufA, N, 128, 256, 2);
  // GRU1 fused (fat-tile role-split)
  k_fgru<256, 1, 0><<<MB * 4, 512, 0, stream>>>(bufA, p0b, Wih1b, Whh1b, bih1, bhh1,
                                                emb0, emb0b, nullptr, nullptr, nullptr, N, 4);
  // GCN2: linear first (256->128, fp8 out), then aggregate with bias+leaky
  k_mm<0, 0, 1><<<MB, 256, 0, stream>>>(emb0b, WtC2, nullptr, buf8, N, 256, 128, 1);
  k_agg128<1><<<AB, 256, 0, stream>>>(buf8, rp, csrc, cw, dis, bc2, bufD, N);
  // GRU2 fused + folded post-head
  k_fgru<128, 0, 1><<<MB * 2, 512, 0, stream>>>(bufD, p1b, Wih2b, Whh2b, bih2, bhh2,
                                                emb1, nullptr, Wpost, bpost, outv, N, 2);
}

// Round 13
// 741.938 us; speedup vs baseline: 1.5634x; 1.5634x over previous
//
#include <hip/hip_runtime.h>
#include <cstdint>
#include <cstddef>

typedef __bf16 bf16x8 __attribute__((ext_vector_type(8)));
typedef float f32x4 __attribute__((ext_vector_type(4)));
typedef float f32x2 __attribute__((ext_vector_type(2)));
typedef unsigned short us16;

__device__ __forceinline__ float lrelu(float v) { return v >= 0.0f ? v : 0.01f * v; }
__device__ __forceinline__ float fsigmoid(float x) {
  x = fminf(fmaxf(x, -30.0f), 30.0f);
  return 1.0f / (1.0f + __expf(-x));
}
__device__ __forceinline__ float ftanh(float x) {
  x = fminf(fmaxf(x, -15.0f), 15.0f);
  float e = __expf(2.0f * x);
  return (e - 1.0f) / (e + 1.0f);
}
__device__ __forceinline__ us16 f2b(float f) {
  unsigned int u = __builtin_bit_cast(unsigned int, f);
  u = (u + 0x7fffu + ((u >> 16) & 1u)) >> 16;
  return (us16)u;
}
__device__ __forceinline__ float b2f(us16 h) {
  unsigned int u = ((unsigned int)h) << 16;
  return __builtin_bit_cast(float, u);
}
__device__ __forceinline__ unsigned pk2(float a, float b) {
  return (unsigned)f2b(a) | ((unsigned)f2b(b) << 16);
}
// fp8 e4m3 (OCP) encode/decode via gfx950 HW converts
__device__ __forceinline__ unsigned char f2f8(float v) {
  return (unsigned char)(__builtin_amdgcn_cvt_pk_fp8_f32(v, v, 0, false) & 0xFF);
}
__device__ __forceinline__ void unpf8w(unsigned w, float* t) {
  f32x2 p0 = __builtin_amdgcn_cvt_pk_f32_fp8(w, false);
  f32x2 p1 = __builtin_amdgcn_cvt_pk_f32_fp8(w, true);
  t[0] = p0.x; t[1] = p0.y; t[2] = p1.x; t[3] = p1.y;
}
__device__ __forceinline__ void unpf8x16(int4 v, float* t) {
  unpf8w((unsigned)v.x, t);
  unpf8w((unsigned)v.y, t + 4);
  unpf8w((unsigned)v.z, t + 8);
  unpf8w((unsigned)v.w, t + 12);
}

// async global->LDS, 16B per lane
__device__ __forceinline__ void stage16(const us16* gsrc, us16* ldst) {
  __builtin_amdgcn_global_load_lds(
      (const __attribute__((address_space(1))) unsigned int*)(const void*)gsrc,
      (__attribute__((address_space(3))) unsigned int*)(void*)ldst, 16, 0, 0);
}
// 128B-row tiles (Kstep=64): slot = chunk ^ (row&7)
__device__ __forceinline__ bf16x8 frag_rd(const us16* base, int row, int byte_in_row) {
  int byte = row * 128 + (byte_in_row ^ ((row & 7) << 4));
  return *(const bf16x8*)((const char*)base + byte);
}
// 64B-row tiles (Kstep=32): slot = chunk ^ ((row>>1)&3)
__device__ __forceinline__ bf16x8 frd32(const us16* tilebase, int row, int ck16) {
  int slot = ck16 ^ ((row >> 1) & 3);
  return *(const bf16x8*)(tilebase + row * 32 + slot * 8);
}

// ---------------- degree / CSR build ----------------
__global__ void k_deg(const int* __restrict__ dst, int* __restrict__ indeg, int E) {
  int e = blockIdx.x * 256 + threadIdx.x;
  if (e < E) atomicAdd(&indeg[dst[e]], 1);
}

__global__ __launch_bounds__(1024) void k_scan1(const int* __restrict__ v, int* __restrict__ rp,
                                                int* __restrict__ part, float* __restrict__ dis, int n) {
  __shared__ int wsum[16];
  int base = blockIdx.x << 10;
  int t = threadIdx.x, lane = t & 63, wv = t >> 6;
  int val = (base + t < n) ? v[base + t] : 0;
  if (base + t < n) dis[base + t] = rsqrtf((float)(val + 1));
  int s = val;
  #pragma unroll
  for (int off = 1; off < 64; off <<= 1) {
    int u = __shfl_up(s, off);
    if (lane >= off) s += u;
  }
  if (lane == 63) wsum[wv] = s;
  __syncthreads();
  int wadd = 0;
  #pragma unroll
  for (int w = 0; w < 16; ++w) wadd += (w < wv) ? wsum[w] : 0;
  if (base + t < n) rp[base + t] = wadd + s - val;
  if (t == 0) {
    int tot = 0;
    #pragma unroll
    for (int w = 0; w < 16; ++w) tot += wsum[w];
    part[blockIdx.x] = tot;
  }
}

__global__ __launch_bounds__(1024) void k_scan2(int* __restrict__ p, int nc) {
  __shared__ int wsum[16];
  int t = threadIdx.x, lane = t & 63, wv = t >> 6;
  int val = (t < nc) ? p[t] : 0;
  int s = val;
  #pragma unroll
  for (int off = 1; off < 64; off <<= 1) {
    int u = __shfl_up(s, off);
    if (lane >= off) s += u;
  }
  if (lane == 63) wsum[wv] = s;
  __syncthreads();
  int wadd = 0;
  #pragma unroll
  for (int w = 0; w < 16; ++w) wadd += (w < wv) ? wsum[w] : 0;
  if (t < nc) p[t] = wadd + s - val;
}

__global__ void k_scan3(int* __restrict__ rp, const int* __restrict__ part,
                        int* __restrict__ cursor, int n, int total) {
  int i = blockIdx.x * 256 + threadIdx.x;
  if (i < n) {
    int v = rp[i] + part[i >> 10];
    rp[i] = v;
    cursor[i] = v;
  } else if (i == n) {
    rp[n] = total;
  }
}

__global__ void k_fill(const int* __restrict__ src, const int* __restrict__ dst,
                       const float* __restrict__ dis, int* __restrict__ cursor,
                       int* __restrict__ csrc, float* __restrict__ cw, int E) {
  int e = blockIdx.x * 256 + threadIdx.x;
  if (e >= E) return;
  int s = src[e], d = dst[e];
  int pos = atomicAdd(&cursor[d], 1);
  csrc[pos] = s;
  cw[pos] = dis[s] * dis[d];
}

// ---------------- repack: all three activation casts in one launch ----------------
__global__ void k_castall(const float* __restrict__ x, const float* __restrict__ p0,
                          const float* __restrict__ p1,
                          us16* __restrict__ xb, us16* __restrict__ p0b,
                          us16* __restrict__ p1b, int N) {
  int i = (blockIdx.x * 256 + threadIdx.x) * 4;
  const int nx = N * 128, n0 = N * 256;
  const float* src;
  us16* dst;
  int off;
  if (i < nx) { src = x; dst = xb; off = i; }
  else if (i < nx + n0) { src = p0; dst = p0b; off = i - nx; }
  else if (i < nx + n0 + nx) { src = p1; dst = p1b; off = i - nx - n0; }
  else return;
  float4 v = *(const float4*)(src + off);
  *(ushort4*)(dst + off) = make_ushort4(f2b(v.x), f2b(v.y), f2b(v.z), f2b(v.w));
}

__global__ void k_prepw(const float* __restrict__ Wih1, const float* __restrict__ Whh1,
                        const float* __restrict__ Wih2, const float* __restrict__ Whh2,
                        const float* __restrict__ Wp1, const float* __restrict__ Wp2,
                        const float* __restrict__ Wc1, const float* __restrict__ Wc2,
                        us16* __restrict__ Wih1b, us16* __restrict__ Whh1b,
                        us16* __restrict__ Wih2b, us16* __restrict__ Whh2b,
                        us16* __restrict__ WtP1, us16* __restrict__ WtP2,
                        us16* __restrict__ WtC1, us16* __restrict__ WtC2) {
  int e = blockIdx.x * 256 + threadIdx.x;
  if (e < 196608) { Wih1b[e] = f2b(Wih1[e]); return; }
  e -= 196608;
  if (e < 196608) { Whh1b[e] = f2b(Whh1[e]); return; }
  e -= 196608;
  if (e < 49152) { Wih2b[e] = f2b(Wih2[e]); return; }
  e -= 49152;
  if (e < 49152) { Whh2b[e] = f2b(Whh2[e]); return; }
  e -= 49152;
  if (e < 32768) { int r = e & 127, c = e >> 7; WtP1[e] = f2b(Wp1[(size_t)r * 256 + c]); return; }
  e -= 32768;
  if (e < 32768) { int r = e & 255, c = e >> 8; WtP2[e] = f2b(Wp2[(size_t)r * 128 + c]); return; }
  e -= 32768;
  if (e < 32768) { int r = e & 127, c = e >> 7; WtC1[e] = f2b(Wc1[(size_t)r * 256 + c]); return; }
  e -= 32768;
  if (e < 32768) { int r = e & 255, c = e >> 8; WtC2[e] = f2b(Wc2[(size_t)r * 128 + c]); }
}

// ---------------- bf16 MFMA GEMM (r11 T4 version): C = act(A @ Bt^T + bias) ----------------
template<int ACT, int BIAS, int OF8>
__global__ __launch_bounds__(256) void k_mm(const us16* __restrict__ A,
                                            const us16* __restrict__ Bt,
                                            const float* __restrict__ bias,
                                            void* __restrict__ Cout,
                                            int M, int K, int Nc, int ny) {
  __shared__ __align__(16) us16 lds[2][2 * 8192];
  const int bm = (blockIdx.x / ny) * 128;
  const int bn = (blockIdx.x % ny) * 128;
  const int tid = threadIdx.x;
  const int lane = tid & 63;
  const int wave = tid >> 6;
  const int wm = (wave >> 1) * 64;
  const int wn = (wave & 1) * 64;
  const int lr = lane & 15;
  const int lk = lane >> 4;
  const int srow = lane >> 3;
  const int schk = (lane & 7) ^ srow;
  f32x4 acc[4][4] = {};

  auto stage = [&](int k0, us16* buf) {
    #pragma unroll
    for (int it = 0; it < 4; ++it) {
      int r8 = (wave * 4 + it) * 8;
      int ar = bm + r8 + srow; if (ar >= M) ar = M - 1;
      stage16(A + (size_t)ar * K + k0 + schk * 8, buf + r8 * 64);
      stage16(Bt + (size_t)(bn + r8 + srow) * K + k0 + schk * 8, buf + 8192 + r8 * 64);
    }
  };

  const int nk = K >> 6;
  stage(0, lds[0]);
  for (int t = 0; t < nk; ++t) {
    us16* cur = lds[t & 1];
    if (t + 1 < nk) {
      if (t > 0) {
        asm volatile("s_waitcnt lgkmcnt(0)" ::: "memory");
        __builtin_amdgcn_s_barrier();
      }
      stage((t + 1) << 6, lds[(t + 1) & 1]);
      asm volatile("s_waitcnt vmcnt(8)" ::: "memory");
    } else {
      asm volatile("s_waitcnt vmcnt(0)" ::: "memory");
    }
    __builtin_amdgcn_s_barrier();
    #pragma unroll
    for (int kk = 0; kk < 2; ++kk) {
      bf16x8 af[4], bq[4];
      #pragma unroll
      for (int i = 0; i < 4; ++i) af[i] = frag_rd(cur, wm + i * 16 + lr, kk * 64 + lk * 16);
      #pragma unroll
      for (int j = 0; j < 4; ++j) bq[j] = frag_rd(cur + 8192, wn + j * 16 + lr, kk * 64 + lk * 16);
      #pragma unroll
      for (int i = 0; i < 4; ++i)
        #pragma unroll
        for (int j = 0; j < 4; ++j)
          acc[i][j] = __builtin_amdgcn_mfma_f32_16x16x32_bf16(af[i], bq[j], acc[i][j], 0, 0, 0);
    }
  }
  float bb[4];
  #pragma unroll
  for (int j = 0; j < 4; ++j) bb[j] = BIAS ? bias[bn + wn + j * 16 + lr] : 0.0f;
  #pragma unroll
  for (int i = 0; i < 4; ++i) {
    #pragma unroll
    for (int q = 0; q < 4; ++q) {
      int row = bm + wm + i * 16 + lk * 4 + q;
      if (row < M) {
        #pragma unroll
        for (int j = 0; j < 4; ++j) {
          int col = bn + wn + j * 16 + lr;
          float v = acc[i][j][q] + bb[j];
          if (ACT) v = lrelu(v);
          if (OF8) ((unsigned char*)Cout)[(size_t)row * Nc + col] = f2f8(v);
          else ((us16*)Cout)[(size_t)row * Nc + col] = f2b(v);
        }
      }
    }
  }
}

// ---------------- CSR aggregation, F=128, fp8 payload, 8 lanes/node x int4 (16B) ----------------
template<int ACT>
__global__ __launch_bounds__(256) void k_agg128(const unsigned char* __restrict__ hw,
                                                const int* __restrict__ rp,
                                                const int* __restrict__ csrc, const float* __restrict__ cw,
                                                const float* __restrict__ dis, const float* __restrict__ bias,
                                                us16* __restrict__ outp, int M) {
  int node = blockIdx.x * 32 + (threadIdx.x >> 3);
  int l = threadIdx.x & 7;
  if (node >= M) return;
  const unsigned char* base = hw + l * 16;
  float acc[16], t0[16], t1[16];
  float dn = dis[node];
  float sw = dn * dn;
  {
    int4 v = *(const int4*)(base + (size_t)node * 128);
    unpf8x16(v, t0);
    #pragma unroll
    for (int j = 0; j < 16; ++j) acc[j] = t0[j] * sw;
  }
  int e = rp[node], e1 = rp[node + 1];
  for (; e + 2 <= e1; e += 2) {
    int s0 = csrc[e], s1 = csrc[e + 1];
    float w0 = cw[e], w1 = cw[e + 1];
    int4 v0 = *(const int4*)(base + (size_t)s0 * 128);
    int4 v1 = *(const int4*)(base + (size_t)s1 * 128);
    unpf8x16(v0, t0);
    unpf8x16(v1, t1);
    #pragma unroll
    for (int j = 0; j < 16; ++j) acc[j] = fmaf(w0, t0[j], acc[j]);
    #pragma unroll
    for (int j = 0; j < 16; ++j) acc[j] = fmaf(w1, t1[j], acc[j]);
  }
  if (e < e1) {
    int s0 = csrc[e];
    float w0 = cw[e];
    int4 v0 = *(const int4*)(base + (size_t)s0 * 128);
    unpf8x16(v0, t0);
    #pragma unroll
    for (int j = 0; j < 16; ++j) acc[j] = fmaf(w0, t0[j], acc[j]);
  }
  if (ACT) {
    #pragma unroll
    for (int c = 0; c < 4; ++c) {
      float4 b4 = *(const float4*)(bias + l * 16 + c * 4);
      acc[c * 4 + 0] = lrelu(acc[c * 4 + 0] + b4.x);
      acc[c * 4 + 1] = lrelu(acc[c * 4 + 1] + b4.y);
      acc[c * 4 + 2] = lrelu(acc[c * 4 + 2] + b4.z);
      acc[c * 4 + 3] = lrelu(acc[c * 4 + 3] + b4.w);
    }
  }
  us16* orow = outp + (size_t)node * 128 + l * 16;
  int4 o0, o1;
  o0.x = (int)pk2(acc[0], acc[1]);  o0.y = (int)pk2(acc[2], acc[3]);
  o0.z = (int)pk2(acc[4], acc[5]);  o0.w = (int)pk2(acc[6], acc[7]);
  o1.x = (int)pk2(acc[8], acc[9]);  o1.y = (int)pk2(acc[10], acc[11]);
  o1.z = (int)pk2(acc[12], acc[13]); o1.w = (int)pk2(acc[14], acc[15]);
  *(int4*)(orow) = o0;
  *(int4*)(orow + 8) = o1;
}

// ---------------- fused GRU cell, role-split (MFMA), T4 counted-vmcnt (r11-proven) ----------------
template<int H, int WB, int PH>
__global__ __launch_bounds__(512) void k_fgru(const us16* __restrict__ xb, const us16* __restrict__ hb,
                                              const us16* __restrict__ Wih, const us16* __restrict__ Whh,
                                              const float* __restrict__ bih, const float* __restrict__ bhh,
                                              float* __restrict__ emb, us16* __restrict__ embb,
                                              const float* __restrict__ Wpost, const float* __restrict__ bpost,
                                              float* __restrict__ outv, int M, int ny) {
  __shared__ __align__(16) us16 lds[2][14336];  // 28KB each: x[128x32] | h[128x32] | 6x w[32x32]
  const int nwg = gridDim.x;
  int bid = blockIdx.x;
  {  // bijective XCD-chunked remap
    int q8 = nwg >> 3, r8 = nwg & 7;
    int xc = bid & 7, ix = bid >> 3;
    bid = (xc < r8 ? xc * (q8 + 1) : r8 * (q8 + 1) + (xc - r8) * q8) + ix;
  }
  const int bn = (bid % ny) * 32;
  const int bm = (bid / ny) * 128;
  const int tid = threadIdx.x;
  const int lane = tid & 63, wave = tid >> 6;
  const int pair = wave >> 1;   // 0..3 -> 32-row group
  const int role = wave & 1;    // 0 = gi (x, Wih), 1 = gh (h, Whh)
  const int wm = pair * 32;
  const int lr = lane & 15, lk = lane >> 4;
  const int sl_row = lane >> 2;
  const int sl_chk = (lane & 3) ^ ((lane >> 3) & 3);

  f32x4 acc[3][2][2] = {};

  auto stage_step = [&](int k0, us16* buf) {
    #pragma unroll
    for (int it = 0; it < 4; ++it) {
      int m = wave * 4 + it;
      if (m >= 28) break;  // waves 0-6 issue 4 loads each; wave 7 issues 0
      const us16* src;
      us16* dst;
      if (m < 16) {
        int r0 = (m & 7) * 16;
        int ar = bm + r0 + sl_row; if (ar >= M) ar = M - 1;
        src = (m < 8 ? xb : hb) + (size_t)ar * H + k0 + sl_chk * 8;
        dst = buf + (m < 8 ? 0 : 4096) + r0 * 32;
      } else {
        int wi = m - 16;
        int g6 = wi >> 1;
        int r0 = (wi & 1) * 16;
        const us16* W = (g6 < 3) ? Wih : Whh;
        int gg = (g6 < 3) ? g6 : g6 - 3;
        src = W + (size_t)(gg * H + bn + r0 + sl_row) * H + k0 + sl_chk * 8;
        dst = buf + 8192 + g6 * 1024 + r0 * 32;
      }
      stage16(src, dst);
    }
  };

  const int nk = H >> 5;
  stage_step(0, lds[0]);
  for (int t = 0; t < nk; ++t) {
    us16* cur = lds[t & 1];
    if (t + 1 < nk) {
      if (t > 0) {
        asm volatile("s_waitcnt lgkmcnt(0)" ::: "memory");
        __builtin_amdgcn_s_barrier();
      }
      stage_step((t + 1) << 5, lds[(t + 1) & 1]);
      asm volatile("s_waitcnt vmcnt(4)" ::: "memory");
    } else {
      asm volatile("s_waitcnt vmcnt(0)" ::: "memory");
    }
    __builtin_amdgcn_s_barrier();
    const us16* at = cur + (role ? 4096 : 0);
    bf16x8 a0 = frd32(at, wm + lr, lk);
    bf16x8 a1 = frd32(at, wm + 16 + lr, lk);
    #pragma unroll
    for (int g = 0; g < 3; ++g) {
      const us16* wt = cur + 8192 + (role * 3 + g) * 1024;
      bf16x8 b0 = frd32(wt, lr, lk);
      bf16x8 b1 = frd32(wt, 16 + lr, lk);
      acc[g][0][0] = __builtin_amdgcn_mfma_f32_16x16x32_bf16(a0, b0, acc[g][0][0], 0, 0, 0);
      acc[g][0][1] = __builtin_amdgcn_mfma_f32_16x16x32_bf16(a0, b1, acc[g][0][1], 0, 0, 0);
      acc[g][1][0] = __builtin_amdgcn_mfma_f32_16x16x32_bf16(a1, b0, acc[g][1][0], 0, 0, 0);
      acc[g][1][1] = __builtin_amdgcn_mfma_f32_16x16x32_bf16(a1, b1, acc[g][1][1], 0, 0, 0);
    }
  }
  // ---- exchange: gh waves publish; gi waves combine + epilogue ----
  __syncthreads();
  float* xch = (float*)&lds[0][0];
  if (role) {
    #pragma unroll
    for (int g = 0; g < 3; ++g)
      #pragma unroll
      for (int i = 0; i < 2; ++i)
        #pragma unroll
        for (int j = 0; j < 2; ++j)
          *(f32x4*)&xch[((((pair * 3 + g) * 2 + i) * 2 + j) * 64 + lane) * 4] = acc[g][i][j];
  }
  __syncthreads();
  if (!role) {
    float part[2][4] = {};
    #pragma unroll
    for (int j = 0; j < 2; ++j) {
      int col = bn + j * 16 + lr;
      float bir = bih[col], biz = bih[H + col], bin = bih[2 * H + col];
      float bhr = bhh[col], bhz = bhh[H + col], bhn = bhh[2 * H + col];
      float wps = 0.0f;
      if (PH) wps = Wpost[2 * col] + Wpost[2 * col + 1];
      #pragma unroll
      for (int i = 0; i < 2; ++i) {
        f32x4 gr_ = *(const f32x4*)&xch[((((pair * 3 + 0) * 2 + i) * 2 + j) * 64 + lane) * 4];
        f32x4 gz_ = *(const f32x4*)&xch[((((pair * 3 + 1) * 2 + i) * 2 + j) * 64 + lane) * 4];
        f32x4 gn_ = *(const f32x4*)&xch[((((pair * 3 + 2) * 2 + i) * 2 + j) * 64 + lane) * 4];
        #pragma unroll
        for (int q = 0; q < 4; ++q) {
          int row = bm + wm + i * 16 + lk * 4 + q;
          if (row < M) {
            float r = fsigmoid(acc[0][i][j][q] + bir + gr_[q] + bhr);
            float z = fsigmoid(acc[1][i][j][q] + biz + gz_[q] + bhz);
            float n = ftanh(acc[2][i][j][q] + bin + r * (gn_[q] + bhn));
            float hv = b2f(hb[(size_t)row * H + col]);
            float o = (1.0f - z) * n + z * hv;
            emb[(size_t)row * H + col] = o;
            if (WB) embb[(size_t)row * H + col] = f2b(o);
            if (PH) part[i][q] += o * wps;
          }
        }
      }
    }
    if (PH) {
      float bsum = bpost[0] + bpost[1];
      #pragma unroll
      for (int i = 0; i < 2; ++i)
        #pragma unroll
        for (int q = 0; q < 4; ++q) {
          float v = part[i][q];
          v += __shfl_xor(v, 1); v += __shfl_xor(v, 2);
          v += __shfl_xor(v, 4); v += __shfl_xor(v, 8);
          int row = bm + wm + i * 16 + lk * 4 + q;
          if (lr == 0 && row < M)
            atomicAdd(&outv[row], v + (bn == 0 ? bsum : 0.0f));
        }
    }
  }
}

extern "C" void kernel_launch(void* const* d_in, const int* in_sizes, int n_in,
                              void* d_out, int out_size, void* d_ws, size_t ws_size,
                              hipStream_t stream) {
  const float* x     = (const float*)d_in[0];
  const int*   ei    = (const int*)d_in[1];
  const float* prev0 = (const float*)d_in[2];
  const float* prev1 = (const float*)d_in[3];
  const float* Wp1   = (const float*)d_in[4];
  const float* bp1   = (const float*)d_in[5];
  const float* Wp2   = (const float*)d_in[6];
  const float* bp2   = (const float*)d_in[7];
  const float* Wc1   = (const float*)d_in[8];
  const float* bc1   = (const float*)d_in[9];
  const float* Wc2   = (const float*)d_in[10];
  const float* bc2   = (const float*)d_in[11];
  const float* Wih1  = (const float*)d_in[12];
  const float* Whh1  = (const float*)d_in[13];
  const float* bih1  = (const float*)d_in[14];
  const float* bhh1  = (const float*)d_in[15];
  const float* Wih2  = (const float*)d_in[16];
  const float* Whh2  = (const float*)d_in[17];
  const float* bih2  = (const float*)d_in[18];
  const float* bhh2  = (const float*)d_in[19];
  const float* Wpost = (const float*)d_in[20];
  const float* bpost = (const float*)d_in[21];

  const int N = in_sizes[0] / 128;   // 100000
  const int E = in_sizes[1] / 2;     // 1600000
  const int* srcp = ei;
  const int* dstp = ei + E;

  char* wsb = (char*)d_ws;
  size_t off = 0;
  auto alloc = [&](size_t bytes) -> void* {
    void* p = wsb + off;
    off = (off + bytes + 255) & ~(size_t)255;
    return p;
  };
  float* dis    = (float*)alloc((size_t)N * 4);
  int*   indeg  = (int*)alloc((size_t)N * 4);
  int*   rp     = (int*)alloc((size_t)(N + 1) * 4);
  int*   part   = (int*)alloc((size_t)1024 * 4);
  int*   cursor = (int*)alloc((size_t)N * 4);
  int*   csrc   = (int*)alloc((size_t)E * 4);
  float* cw     = (float*)alloc((size_t)E * 4);
  us16* xb    = (us16*)alloc((size_t)N * 128 * 2);
  us16* p0b   = (us16*)alloc((size_t)N * 256 * 2);
  us16* p1b   = (us16*)alloc((size_t)N * 128 * 2);
  us16* WtP1  = (us16*)alloc((size_t)256 * 128 * 2);
  us16* WtP2  = (us16*)alloc((size_t)128 * 256 * 2);
  us16* WtC1  = (us16*)alloc((size_t)256 * 128 * 2);
  us16* WtC2  = (us16*)alloc((size_t)128 * 256 * 2);
  us16* Wih1b = (us16*)alloc((size_t)768 * 256 * 2);
  us16* Whh1b = (us16*)alloc((size_t)768 * 256 * 2);
  us16* Wih2b = (us16*)alloc((size_t)384 * 128 * 2);
  us16* Whh2b = (us16*)alloc((size_t)384 * 128 * 2);
  us16* bufA  = (us16*)alloc((size_t)N * 256 * 2);           // MLP hidden / GCN1 out (bf16)
  unsigned char* buf8 = (unsigned char*)alloc((size_t)N * 128); // fp8 gather payload
  us16* bufD  = (us16*)alloc((size_t)N * 128 * 2);           // agg out (bf16)
  us16* emb0b = (us16*)alloc((size_t)N * 256 * 2);
  (void)ws_size; (void)n_in; (void)out_size;

  float* outv = (float*)d_out;
  float* emb0 = outv + N;
  float* emb1 = emb0 + (size_t)N * 256;

  // zero the post-head accumulator
  hipMemsetAsync(outv, 0, (size_t)N * 4, stream);

  // activation casts (single launch) + fused weight prep
  k_castall<<<((size_t)N * 512 / 4 + 255) / 256, 256, 0, stream>>>(x, prev0, prev1, xb, p0b, p1b, N);
  k_prepw<<<2432, 256, 0, stream>>>(Wih1, Whh1, Wih2, Whh2, Wp1, Wp2, Wc1, Wc2,
                                    Wih1b, Whh1b, Wih2b, Whh2b, WtP1, WtP2, WtC1, WtC2);

  // CSR build
  hipMemsetAsync(indeg, 0, (size_t)N * 4, stream);
  k_deg<<<(E + 255) / 256, 256, 0, stream>>>(dstp, indeg, E);
  const int NC = (N + 1023) / 1024;  // 98
  k_scan1<<<NC, 1024, 0, stream>>>(indeg, rp, part, dis, N);
  k_scan2<<<1, 1024, 0, stream>>>(part, NC);
  k_scan3<<<(N + 256) / 256, 256, 0, stream>>>(rp, part, cursor, N, E);
  k_fill<<<(E + 255) / 256, 256, 0, stream>>>(srcp, dstp, dis, cursor, csrc, cw, E);

  const int MB = (N + 127) / 128;   // 782
  const int AB = (N + 31) / 32;     // 3125

  // preprocess MLP (MLP2 writes fp8 gather payload)
  k_mm<1, 1, 0><<<MB * 2, 256, 0, stream>>>(xb, WtP1, bp1, bufA, N, 128, 256, 2);
  k_mm<1, 1, 1><<<MB, 256, 0, stream>>>(bufA, WtP2, bp2, buf8, N, 256, 128, 1);
  // GCN1: aggregate FIRST (linearity, fp8 gathers), then linear+bias+leaky
  k_agg128<0><<<AB, 256, 0, stream>>>(buf8, rp, csrc, cw, dis, nullptr, bufD, N);
  k_mm<1, 1, 0><<<MB * 2, 256, 0, stream>>>(bufD, WtC1, bc1, bufA, N, 128, 256, 2);
  // GRU1 fused (role-split, T4 counted-vmcnt)
  k_fgru<256, 1, 0><<<MB * 8, 512, 0, stream>>>(bufA, p0b, Wih1b, Whh1b, bih1, bhh1,
                                                emb0, emb0b, nullptr, nullptr, nullptr, N, 8);
  // GCN2: linear first (256->128, fp8 out), then aggregate with bias+leaky
  k_mm<0, 0, 1><<<MB, 256, 0, stream>>>(emb0b, WtC2, nullptr, buf8, N, 256, 128, 1);
  k_agg128<1><<<AB, 256, 0, stream>>>(buf8, rp, csrc, cw, dis, bc2, bufD, N);
  // GRU2 fused + folded post-head
  k_fgru<128, 0, 1><<<MB * 4, 512, 0, stream>>>(bufD, p1b, Wih2b, Whh2b, bih2, bhh2,
                                                emb1, nullptr, Wpost, bpost, outv, N, 4);
}